// Round 1
// 477.916 us; speedup vs baseline: 5.4058x; 5.4058x over previous
//
#include <hip/hip_runtime.h>
#include <hip/hip_bf16.h>
#include <math.h>

using bf16 = __hip_bfloat16;
typedef __attribute__((ext_vector_type(8))) short bf16x8;
typedef __attribute__((ext_vector_type(4))) float f32x4;

#define BB   4
#define TT   2048
#define DD   1024
#define HH   16
#define HD_  64
#define LAT_ 128
#define RP   32
#define EPS_ 1e-6f

static __device__ __forceinline__ void stf(float* p, float v) { *p = v; }
static __device__ __forceinline__ void stf(bf16* p, float v) { *p = __float2bfloat16(v); }

__global__ __launch_bounds__(256)
void sentinel_kernel(float* __restrict__ out, float val, long long n)
{
    long long i = (long long)blockIdx.x * 256 + threadIdx.x;
    if (i < n) out[i] = val;
}

// ---------------------------------------------------------------------------
// Converters (one-time, memory-bound, ~30 us total)
// ---------------------------------------------------------------------------
__global__ __launch_bounds__(256)
void conv_x_kernel(const float* __restrict__ x, bf16* __restrict__ xb, long long n)
{
    long long i = (long long)blockIdx.x * 256 + threadIdx.x;
    if (i < n) xb[i] = __float2bfloat16(x[i]);
}

// W (K x N fp32 row-major) -> WT (N x K bf16): WT[n*K+k] = W[k*N+n]
__global__ __launch_bounds__(256)
void conv_wT_kernel(const float* __restrict__ W, bf16* __restrict__ WT, int K, int N)
{
    long long idx = (long long)blockIdx.x * 256 + threadIdx.x;
    if (idx >= (long long)K * N) return;
    int k = (int)(idx / N), n = (int)(idx % N);
    WT[(size_t)n * K + k] = __float2bfloat16(W[idx]);
}

// [Wk | Wv] (each 128x512) -> WT (1024 x 128): rows 0..511 = Wk cols,
// rows 512..1023 = Wv cols.
__global__ __launch_bounds__(256)
void conv_wkwv_kernel(const float* __restrict__ Wk, const float* __restrict__ Wv,
                      bf16* __restrict__ WT)
{
    int idx = blockIdx.x * 256 + threadIdx.x;      // 128*1024
    if (idx >= 128 * 1024) return;
    int k = idx >> 10, n = idx & 1023;
    float v = (n < 512) ? Wk[k * 512 + n] : Wv[k * 512 + (n - 512)];
    WT[(size_t)n * 128 + k] = __float2bfloat16(v);
}

// Wo (1024x1024) -> woT (1024 x 512) with row remap: woT[n*512+m] =
// Wo[((m>>5)<<6 | (m&31))*1024 + n]  (skips zero-padded head dims)
__global__ __launch_bounds__(256)
void conv_woT_kernel(const float* __restrict__ Wo, bf16* __restrict__ WT)
{
    int idx = blockIdx.x * 256 + threadIdx.x;      // 512*1024
    if (idx >= 512 * 1024) return;
    int mm = idx >> 10, n = idx & 1023;
    int row = ((mm >> 5) << 6) | (mm & 31);
    WT[(size_t)n * 512 + mm] = __float2bfloat16(Wo[(size_t)row * 1024 + n]);
}

// ---------------------------------------------------------------------------
// MFMA GEMM: C[M,N] = A[M,K] @ B[K,N], A bf16 row-major (M x K), BT bf16
// row-major (N x K). 128x128 tile, BK=32, 256 thr (4 waves).
// Fragment maps (HW-verified): A[m=lane&15][k=quad*8+j],
// BT[n=lane&15][k=quad*8+j], C/D row=quad*4+reg, col=lane&15.
// ---------------------------------------------------------------------------
template <typename OT>
__global__ __launch_bounds__(256)
void gemm_mfma(const short* __restrict__ A, const short* __restrict__ BT,
               OT* __restrict__ C, int M, int N, int K)
{
    __shared__ __align__(16) short As[128][32];
    __shared__ __align__(16) short Bs[128][32];
    const int tid  = threadIdx.x;
    const int wave = tid >> 6, lane = tid & 63;
    const int quad = lane >> 4, l16 = lane & 15;
    const int wr = (wave >> 1) * 64, wc = (wave & 1) * 64;
    const int row0 = blockIdx.y * 128, col0 = blockIdx.x * 128;
    const int srow = tid >> 1, skoff = (tid & 1) * 16;   // staging map

    f32x4 acc[4][4];
    #pragma unroll
    for (int mt = 0; mt < 4; ++mt)
        #pragma unroll
        for (int nt = 0; nt < 4; ++nt)
            acc[mt][nt] = (f32x4){0.f, 0.f, 0.f, 0.f};

    for (int k0 = 0; k0 < K; k0 += 32) {
        const short* ga = A  + (size_t)(row0 + srow) * K + k0 + skoff;
        const short* gb = BT + (size_t)(col0 + srow) * K + k0 + skoff;
        uint4 va0 = *(const uint4*)ga;
        uint4 va1 = *(const uint4*)(ga + 8);
        uint4 vb0 = *(const uint4*)gb;
        uint4 vb1 = *(const uint4*)(gb + 8);
        __syncthreads();
        *(uint4*)&As[srow][skoff]     = va0;
        *(uint4*)&As[srow][skoff + 8] = va1;
        *(uint4*)&Bs[srow][skoff]     = vb0;
        *(uint4*)&Bs[srow][skoff + 8] = vb1;
        __syncthreads();

        bf16x8 af[4], bfv[4];
        #pragma unroll
        for (int mt = 0; mt < 4; ++mt)
            af[mt] = *(const bf16x8*)&As[wr + mt * 16 + l16][quad * 8];
        #pragma unroll
        for (int nt = 0; nt < 4; ++nt)
            bfv[nt] = *(const bf16x8*)&Bs[wc + nt * 16 + l16][quad * 8];
        #pragma unroll
        for (int mt = 0; mt < 4; ++mt)
            #pragma unroll
            for (int nt = 0; nt < 4; ++nt)
                acc[mt][nt] = __builtin_amdgcn_mfma_f32_16x16x32_bf16(
                    af[mt], bfv[nt], acc[mt][nt], 0, 0, 0);
    }

    #pragma unroll
    for (int mt = 0; mt < 4; ++mt)
        #pragma unroll
        for (int nt = 0; nt < 4; ++nt) {
            const int col = col0 + wc + nt * 16 + l16;
            #pragma unroll
            for (int r = 0; r < 4; ++r) {
                const int row = row0 + wr + mt * 16 + quad * 4 + r;
                stf(C + (size_t)row * N + col, acc[mt][nt][r]);
            }
        }
}

// ---------------------------------------------------------------------------
// Q RMSNorm: one wave64 per (bt, h); rms over 64 head dims (bf16 in);
// write first 32 normalized dims, PRE-SCALED by 1/sqrt(64)=0.125, to
// qn bf16 (b,h,t,32).
// ---------------------------------------------------------------------------
__global__ __launch_bounds__(256)
void qrms_kernel(const bf16* __restrict__ qraw, const float* __restrict__ qg,
                 bf16* __restrict__ qn)
{
    const int gid  = blockIdx.x * 256 + threadIdx.x;
    const int lane = gid & 63;
    const int grp  = gid >> 6;
    const int bt   = grp >> 4;
    const int h    = grp & 15;
    float v = __bfloat162float(qraw[(size_t)bt * DD + h * HD_ + lane]);
    float s = v * v;
    #pragma unroll
    for (int off = 32; off; off >>= 1) s += __shfl_xor(s, off, 64);
    const float inv = 1.0f / sqrtf(s * (1.0f / HD_) + EPS_);
    if (lane < RP) {
        const int b = bt >> 11, t = bt & 2047;
        qn[(((size_t)(b * HH + h)) * TT + t) * RP + lane] =
            __float2bfloat16(qg[lane] * v * inv * 0.125f);
    }
}

// ---------------------------------------------------------------------------
// K RMSNorm (lanes 0..31) + V relayout (lanes 32..63) from combined
// kvout fp32 (bt, 1024): cols 0..511 = kpre, 512..1023 = vraw.
// Out: kn/vb bf16 (b,h,t,32).
// ---------------------------------------------------------------------------
__global__ __launch_bounds__(256)
void kv_split_kernel(const float* __restrict__ kvout, const float* __restrict__ kg,
                     bf16* __restrict__ kn, bf16* __restrict__ vout)
{
    const int gid  = blockIdx.x * 256 + threadIdx.x;
    const int lane = gid & 63;
    const int grp  = gid >> 6;
    const int bt   = grp >> 4;
    const int h    = grp & 15;
    const int b = bt >> 11, t = bt & 2047;
    const size_t dst = (((size_t)(b * HH + h)) * TT + t) * RP;
    if (lane < 32) {
        float v = kvout[(size_t)bt * 1024 + h * 32 + lane];
        float s = v * v;
        #pragma unroll
        for (int off = 16; off; off >>= 1) s += __shfl_xor(s, off, 32);
        const float inv = 1.0f / sqrtf(s * (1.0f / RP) + EPS_);
        kn[dst + lane] = __float2bfloat16(kg[lane] * v * inv);
    } else {
        const int j = lane - 32;
        vout[dst + j] = __float2bfloat16(kvout[(size_t)bt * 1024 + 512 + h * 32 + j]);
    }
}

// ---------------------------------------------------------------------------
// V transpose: vb (bh, t, 32) -> vT (bh, 32, 2048). LDS tile 64x32,
// coalesced in and out. ~16 MB r+w, a few us.
// ---------------------------------------------------------------------------
__global__ __launch_bounds__(256)
void vtrans_kernel(const bf16* __restrict__ vb, bf16* __restrict__ vT)
{
    __shared__ __align__(16) short tile[32][72];   // +8 pad vs bank conflicts
    const int bh = blockIdx.y;
    const int t0 = blockIdx.x * 64;
    const int tid = threadIdx.x;
    const int tl = tid >> 2, c0 = (tid & 3) * 8;
    bf16x8 v = *(const bf16x8*)(vb + ((size_t)bh * TT + t0 + tl) * RP + c0);
    #pragma unroll
    for (int j = 0; j < 8; ++j) tile[c0 + j][tl] = v[j];
    __syncthreads();
    const int c = tid >> 3, tt = (tid & 7) * 8;
    bf16x8 o = *(const bf16x8*)&tile[c][tt];
    *(bf16x8*)(vT + ((size_t)bh * RP + c) * TT + t0 + tt) = o;
}

// ---------------------------------------------------------------------------
// Flash-style MFMA attention. Grid (32 q-tiles, 64 bh), 256 thr = 4 waves.
// Each wave owns 16 q-rows; KVBLK=64 per iteration. ROPE=32 == MFMA K dim.
// qn pre-scaled by 1/sqrt(64). Fragment maps identical to gemm_mfma
// (HW-verified): A[m=l16][k=quad*8+j], B[n=l16][k=quad*8+j],
// D row=quad*4+r, col=l16.
// Per-wave P buffer [16][72] bf16 (144 B row stride: 16B-aligned reads,
// bank-floor ds_read_b128). No inter-wave sharing -> no __syncthreads.
// Output: compact bf16 att (b, t, h*32+c).
// ---------------------------------------------------------------------------
__global__ __launch_bounds__(256)
void attn_mfma(const bf16* __restrict__ qn, const bf16* __restrict__ kn,
               const bf16* __restrict__ vT, bf16* __restrict__ att)
{
    __shared__ __align__(16) bf16 P_lds[4][16][72];
    const int tid  = threadIdx.x;
    const int wave = tid >> 6, lane = tid & 63;
    const int quad = lane >> 4, l16 = lane & 15;
    const int qt = (TT / 64 - 1) - (int)blockIdx.x;   // heavy tiles first
    const int bh = blockIdx.y;
    const int q0 = qt * 64;
    const int qbase = q0 + wave * 16;

    const bf16* knb = kn + (size_t)bh * TT * RP;
    const bf16* vtb = vT + (size_t)bh * RP * TT;

    // Q fragment: rows qbase+l16, dims quad*8..quad*8+7 (one 16B load)
    bf16x8 qf = *(const bf16x8*)(qn + ((size_t)bh * TT + qbase + l16) * RP + quad * 8);

    float m[4]  = {-1e30f, -1e30f, -1e30f, -1e30f};
    float lsum[4] = {0.f, 0.f, 0.f, 0.f};
    f32x4 oacc[2];
    oacc[0] = (f32x4){0.f, 0.f, 0.f, 0.f};
    oacc[1] = (f32x4){0.f, 0.f, 0.f, 0.f};

    for (int st = 0; st <= qt; ++st) {
        const int s0 = st * 64;

        // ---- QK^T: 4 sub-tiles of 16 s-cols, K=32 in one MFMA each ----
        f32x4 sc[4];
        #pragma unroll
        for (int sub = 0; sub < 4; ++sub) {
            bf16x8 kf = *(const bf16x8*)(knb + (size_t)(s0 + sub * 16 + l16) * RP + quad * 8);
            sc[sub] = __builtin_amdgcn_mfma_f32_16x16x32_bf16(
                qf, kf, (f32x4){0.f, 0.f, 0.f, 0.f}, 0, 0, 0);
        }

        // ---- causal mask (only possible on/near diagonal for this wave) ----
        if (s0 + 63 > qbase) {
            #pragma unroll
            for (int sub = 0; sub < 4; ++sub) {
                const int s = s0 + sub * 16 + l16;
                #pragma unroll
                for (int r = 0; r < 4; ++r)
                    if (s > qbase + quad * 4 + r) sc[sub][r] = -1e30f;
            }
        }

        // ---- online softmax: rows live in 16-lane groups (fixed quad) ----
        #pragma unroll
        for (int r = 0; r < 4; ++r) {
            float mx = fmaxf(fmaxf(sc[0][r], sc[1][r]), fmaxf(sc[2][r], sc[3][r]));
            #pragma unroll
            for (int off = 8; off; off >>= 1) mx = fmaxf(mx, __shfl_xor(mx, off, 64));
            const float mnew = fmaxf(m[r], mx);
            const float scale = __expf(m[r] - mnew);   // 0 on first tile
            lsum[r] *= scale;
            oacc[0][r] *= scale;
            oacc[1][r] *= scale;
            m[r] = mnew;
        }

        float rs[4] = {0.f, 0.f, 0.f, 0.f};
        #pragma unroll
        for (int sub = 0; sub < 4; ++sub)
            #pragma unroll
            for (int r = 0; r < 4; ++r) {
                const float p = __expf(sc[sub][r] - m[r]);
                rs[r] += p;
                P_lds[wave][quad * 4 + r][sub * 16 + l16] = __float2bfloat16(p);
            }
        #pragma unroll
        for (int r = 0; r < 4; ++r) {
            float s = rs[r];
            #pragma unroll
            for (int off = 8; off; off >>= 1) s += __shfl_xor(s, off, 64);
            lsum[r] += s;
        }

        // ---- PV: P[16q x 64s] @ V[64s x 32c] = 2 ks-slices x 2 col-halves ----
        #pragma unroll
        for (int ks = 0; ks < 2; ++ks) {
            bf16x8 pf = *(const bf16x8*)&P_lds[wave][l16][ks * 32 + quad * 8];
            #pragma unroll
            for (int half = 0; half < 2; ++half) {
                bf16x8 vf = *(const bf16x8*)(vtb + (size_t)(half * 16 + l16) * TT
                                             + s0 + ks * 32 + quad * 8);
                oacc[half] = __builtin_amdgcn_mfma_f32_16x16x32_bf16(
                    pf, vf, oacc[half], 0, 0, 0);
            }
        }
    }

    // ---- epilogue: out[q][c] / l, compact layout (b, t, h*32+c) ----
    const int b = bh >> 4, h = bh & 15;
    #pragma unroll
    for (int r = 0; r < 4; ++r) {
        const float inv = 1.0f / lsum[r];
        const int t = qbase + quad * 4 + r;
        bf16* op = att + ((size_t)(b * TT + t)) * 512 + h * 32;
        op[l16]      = __float2bfloat16(oacc[0][r] * inv);
        op[16 + l16] = __float2bfloat16(oacc[1][r] * inv);
    }
}

// ---------------------------------------------------------------------------
// Workspace (BYTE offsets from base = d_ws + 64; fits verified 60 MB):
//   xb    bf16 [0, 16777216)            (dead after GEMM kvb)
//   wqT   bf16 [16777216, 18874368)     (dead after GEMM1)
//   wkvT  bf16 [18874368, 19136512)     (dead after GEMM kvb)
//   qrawb bf16 [19136512, 35913728)     (dead after qrms)
//   kvb   bf16 [33554432, 35651584)     (alias in dead qrawb tail)
//   kvout fp32 [0, 33554432)            (alias over dead xb/wqT/wkvT/qrawb-head)
//   att_b bf16 [0, 8388608)             (alias over dead kvout)
//   vTb   bf16 [8388608, 16777216)      (alias over dead kvout, after kv_split)
//   qn    bf16 [35913728, 44302336)
//   kn    bf16 [44302336, 52690944)
//   vb    bf16 [52690944, 61079552)
//   wkwvT bf16 [61079552, 61341696)
//   woT   bf16 [61341696, 62390272)
// ---------------------------------------------------------------------------
extern "C" void kernel_launch(void* const* d_in, const int* in_sizes, int n_in,
                              void* d_out, int out_size, void* d_ws, size_t ws_size,
                              hipStream_t stream)
{
    float* out = (float*)d_out;                     // FP32 output
    const long long NOUT = (long long)BB * TT * DD;
    const int outgrid = (int)((NOUT + 255) / 256);

    static const long long expect[8] =
        {8388608, 1048576, 131072, 65536, 65536, 1048576, 64, 32};
    if (n_in != 8) {
        sentinel_kernel<<<outgrid, 256, 0, stream>>>(out, 20000.0f + 100.0f * n_in, NOUT);
        return;
    }
    for (int i = 0; i < 8; ++i) {
        if ((long long)in_sizes[i] != expect[i]) {
            sentinel_kernel<<<outgrid, 256, 0, stream>>>(out, 10000.0f + 1000.0f * i, NOUT);
            return;
        }
    }
    if (ws_size < 62914624ULL) {
        sentinel_kernel<<<outgrid, 256, 0, stream>>>(
            out, 30000.0f + (float)(ws_size >> 20), NOUT);
        return;
    }
    if (out_size != 8388608) {
        sentinel_kernel<<<outgrid, 256, 0, stream>>>(
            out, 512.0f * (1.0f + (float)(out_size >> 20)), NOUT);
        return;
    }

    const float* x   = (const float*)d_in[0];
    const float* Wq  = (const float*)d_in[1];
    const float* Wkv = (const float*)d_in[2];
    const float* Wk  = (const float*)d_in[3];
    const float* Wv  = (const float*)d_in[4];
    const float* Wo  = (const float*)d_in[5];
    const float* qg  = (const float*)d_in[6];
    const float* kg  = (const float*)d_in[7];

    char* base = (char*)d_ws + 64;
    bf16*  xb    = (bf16*)(base + 0);
    bf16*  wqT   = (bf16*)(base + 16777216);
    bf16*  wkvT  = (bf16*)(base + 18874368);
    bf16*  qrawb = (bf16*)(base + 19136512);
    bf16*  kvb   = (bf16*)(base + 33554432);
    float* kvout = (float*)(base + 0);
    bf16*  att_b = (bf16*)(base + 0);
    bf16*  vTb   = (bf16*)(base + 8388608);
    bf16*  qn    = (bf16*)(base + 35913728);
    bf16*  kn    = (bf16*)(base + 44302336);
    bf16*  vb    = (bf16*)(base + 52690944);
    bf16*  wkwvT = (bf16*)(base + 61079552);
    bf16*  woT   = (bf16*)(base + 61341696);

    const int BT = BB * TT;                    // 8192

    // 0. converts
    conv_x_kernel<<<outgrid, 256, 0, stream>>>(x, xb, NOUT);
    conv_wT_kernel<<<4096, 256, 0, stream>>>(Wq, wqT, 1024, 1024);
    conv_wT_kernel<<<512, 256, 0, stream>>>(Wkv, wkvT, 1024, 128);
    conv_wkwv_kernel<<<512, 256, 0, stream>>>(Wk, Wv, wkwvT);
    conv_woT_kernel<<<2048, 256, 0, stream>>>(Wo, woT);

    // 1. qrawb = xb @ Wq (MFMA), 8192x1024, K=1024
    gemm_mfma<bf16><<<dim3(8, 64), 256, 0, stream>>>(
        (const short*)xb, (const short*)wqT, qrawb, BT, DD, DD);
    // 2. qn = rmsnorm_64(qrawb)[:32] * 0.125
    qrms_kernel<<<(BT * HH * 64) / 256, 256, 0, stream>>>(qrawb, qg, qn);
    // 3. kvb = xb @ Wkv (MFMA), 8192x128, K=1024
    gemm_mfma<bf16><<<dim3(1, 64), 256, 0, stream>>>(
        (const short*)xb, (const short*)wkvT, kvb, BT, LAT_, DD);
    // 4. kvout = kvb @ [Wk|Wv] (MFMA), 8192x1024, K=128
    gemm_mfma<float><<<dim3(8, 64), 256, 0, stream>>>(
        (const short*)kvb, (const short*)wkwvT, kvout, BT, 2 * 512, LAT_);
    // 5. kn/vb from kvout
    kv_split_kernel<<<(BT * HH * 64) / 256, 256, 0, stream>>>(kvout, kg, kn, vb);
    // 5.5 vT = transpose(vb): (bh,t,32) -> (bh,32,2048)
    vtrans_kernel<<<dim3(32, 64), 256, 0, stream>>>(vb, vTb);
    // 6. flash MFMA attention -> att_b bf16 (bt, 512)
    attn_mfma<<<dim3(32, 64), 256, 0, stream>>>(qn, kn, vTb, att_b);
    // 7. out = att_b @ Wo_remap (MFMA), 8192x1024, K=512
    gemm_mfma<float><<<dim3(8, 64), 256, 0, stream>>>(
        (const short*)att_b, (const short*)woT, out, BT, DD, 512);
}

// Round 3
// 351.813 us; speedup vs baseline: 7.3434x; 1.3584x over previous
//
#include <hip/hip_runtime.h>
#include <hip/hip_bf16.h>
#include <math.h>

using bf16 = __hip_bfloat16;
typedef __attribute__((ext_vector_type(8))) short bf16x8;
typedef __attribute__((ext_vector_type(4))) float f32x4;

#define BB   4
#define TT   2048
#define DD   1024
#define HH   16
#define HD_  64
#define LAT_ 128
#define RP   32
#define EPS_ 1e-6f

static __device__ __forceinline__ void stf(float* p, float v) { *p = v; }
static __device__ __forceinline__ void stf(bf16* p, float v) { *p = __float2bfloat16(v); }

__global__ __launch_bounds__(256)
void sentinel_kernel(float* __restrict__ out, float val, long long n)
{
    long long i = (long long)blockIdx.x * 256 + threadIdx.x;
    if (i < n) out[i] = val;
}

// ---------------------------------------------------------------------------
// Converters
// ---------------------------------------------------------------------------
__global__ __launch_bounds__(256)
void conv_x_kernel(const float* __restrict__ x, bf16* __restrict__ xb, long long n)
{
    long long i = (long long)blockIdx.x * 256 + threadIdx.x;
    if (i < n) xb[i] = __float2bfloat16(x[i]);
}

__global__ __launch_bounds__(256)
void conv_wT_kernel(const float* __restrict__ W, bf16* __restrict__ WT, int K, int N)
{
    long long idx = (long long)blockIdx.x * 256 + threadIdx.x;
    if (idx >= (long long)K * N) return;
    int k = (int)(idx / N), n = (int)(idx % N);
    WT[(size_t)n * K + k] = __float2bfloat16(W[idx]);
}

__global__ __launch_bounds__(256)
void conv_wkwv_kernel(const float* __restrict__ Wk, const float* __restrict__ Wv,
                      bf16* __restrict__ WT)
{
    int idx = blockIdx.x * 256 + threadIdx.x;      // 128*1024
    if (idx >= 128 * 1024) return;
    int k = idx >> 10, n = idx & 1023;
    float v = (n < 512) ? Wk[k * 512 + n] : Wv[k * 512 + (n - 512)];
    WT[(size_t)n * 128 + k] = __float2bfloat16(v);
}

__global__ __launch_bounds__(256)
void conv_woT_kernel(const float* __restrict__ Wo, bf16* __restrict__ WT)
{
    int idx = blockIdx.x * 256 + threadIdx.x;      // 512*1024
    if (idx >= 512 * 1024) return;
    int mm = idx >> 10, n = idx & 1023;
    int row = ((mm >> 5) << 6) | (mm & 31);
    WT[(size_t)n * 512 + mm] = __float2bfloat16(Wo[(size_t)row * 1024 + n]);
}

// ---------------------------------------------------------------------------
// MFMA GEMM (R1 harness-verified): C[M,N] = A[M,K] @ B[K,N], A bf16
// row-major (M x K), BT bf16 row-major (N x K). 128x128 tile, BK=32,
// 256 thr (4 waves). Fragment maps (HW-verified): A[m=lane&15][k=quad*8+j],
// BT[n=lane&15][k=quad*8+j], C/D row=quad*4+reg, col=lane&15.
// ---------------------------------------------------------------------------
template <typename OT>
__global__ __launch_bounds__(256)
void gemm_mfma(const short* __restrict__ A, const short* __restrict__ BT,
               OT* __restrict__ C, int M, int N, int K)
{
    __shared__ __align__(16) short As[128][32];
    __shared__ __align__(16) short Bs[128][32];
    const int tid  = threadIdx.x;
    const int wave = tid >> 6, lane = tid & 63;
    const int quad = lane >> 4, l16 = lane & 15;
    const int wr = (wave >> 1) * 64, wc = (wave & 1) * 64;
    const int row0 = blockIdx.y * 128, col0 = blockIdx.x * 128;
    const int srow = tid >> 1, skoff = (tid & 1) * 16;   // staging map

    f32x4 acc[4][4];
    #pragma unroll
    for (int mt = 0; mt < 4; ++mt)
        #pragma unroll
        for (int nt = 0; nt < 4; ++nt)
            acc[mt][nt] = (f32x4){0.f, 0.f, 0.f, 0.f};

    for (int k0 = 0; k0 < K; k0 += 32) {
        const short* ga = A  + (size_t)(row0 + srow) * K + k0 + skoff;
        const short* gb = BT + (size_t)(col0 + srow) * K + k0 + skoff;
        uint4 va0 = *(const uint4*)ga;
        uint4 va1 = *(const uint4*)(ga + 8);
        uint4 vb0 = *(const uint4*)gb;
        uint4 vb1 = *(const uint4*)(gb + 8);
        __syncthreads();
        *(uint4*)&As[srow][skoff]     = va0;
        *(uint4*)&As[srow][skoff + 8] = va1;
        *(uint4*)&Bs[srow][skoff]     = vb0;
        *(uint4*)&Bs[srow][skoff + 8] = vb1;
        __syncthreads();

        bf16x8 af[4], bfv[4];
        #pragma unroll
        for (int mt = 0; mt < 4; ++mt)
            af[mt] = *(const bf16x8*)&As[wr + mt * 16 + l16][quad * 8];
        #pragma unroll
        for (int nt = 0; nt < 4; ++nt)
            bfv[nt] = *(const bf16x8*)&Bs[wc + nt * 16 + l16][quad * 8];
        #pragma unroll
        for (int mt = 0; mt < 4; ++mt)
            #pragma unroll
            for (int nt = 0; nt < 4; ++nt)
                acc[mt][nt] = __builtin_amdgcn_mfma_f32_16x16x32_bf16(
                    af[mt], bfv[nt], acc[mt][nt], 0, 0, 0);
    }

    #pragma unroll
    for (int mt = 0; mt < 4; ++mt)
        #pragma unroll
        for (int nt = 0; nt < 4; ++nt) {
            const int col = col0 + wc + nt * 16 + l16;
            #pragma unroll
            for (int r = 0; r < 4; ++r) {
                const int row = row0 + wr + mt * 16 + quad * 4 + r;
                stf(C + (size_t)row * N + col, acc[mt][nt][r]);
            }
        }
}

// ---------------------------------------------------------------------------
// Q RMSNorm: rms over 64 head dims; write first 32 dims * 0.125 to
// qn bf16 (b,h,t,32).
// ---------------------------------------------------------------------------
__global__ __launch_bounds__(256)
void qrms_kernel(const bf16* __restrict__ qraw, const float* __restrict__ qg,
                 bf16* __restrict__ qn)
{
    const int gid  = blockIdx.x * 256 + threadIdx.x;
    const int lane = gid & 63;
    const int grp  = gid >> 6;
    const int bt   = grp >> 4;
    const int h    = grp & 15;
    float v = __bfloat162float(qraw[(size_t)bt * DD + h * HD_ + lane]);
    float s = v * v;
    #pragma unroll
    for (int off = 32; off; off >>= 1) s += __shfl_xor(s, off, 64);
    const float inv = 1.0f / sqrtf(s * (1.0f / HD_) + EPS_);
    if (lane < RP) {
        const int b = bt >> 11, t = bt & 2047;
        qn[(((size_t)(b * HH + h)) * TT + t) * RP + lane] =
            __float2bfloat16(qg[lane] * v * inv * 0.125f);
    }
}

// ---------------------------------------------------------------------------
// K RMSNorm (lanes 0..31) + V relayout (lanes 32..63).
// ---------------------------------------------------------------------------
__global__ __launch_bounds__(256)
void kv_split_kernel(const float* __restrict__ kvout, const float* __restrict__ kg,
                     bf16* __restrict__ kn, bf16* __restrict__ vout)
{
    const int gid  = blockIdx.x * 256 + threadIdx.x;
    const int lane = gid & 63;
    const int grp  = gid >> 6;
    const int bt   = grp >> 4;
    const int h    = grp & 15;
    const int b = bt >> 11, t = bt & 2047;
    const size_t dst = (((size_t)(b * HH + h)) * TT + t) * RP;
    if (lane < 32) {
        float v = kvout[(size_t)bt * 1024 + h * 32 + lane];
        float s = v * v;
        #pragma unroll
        for (int off = 16; off; off >>= 1) s += __shfl_xor(s, off, 32);
        const float inv = 1.0f / sqrtf(s * (1.0f / RP) + EPS_);
        kn[dst + lane] = __float2bfloat16(kg[lane] * v * inv);
    } else {
        const int j = lane - 32;
        vout[dst + j] = __float2bfloat16(kvout[(size_t)bt * 1024 + 512 + h * 32 + j]);
    }
}

// ---------------------------------------------------------------------------
// V transpose: vb (bh, t, 32) -> vT (bh, 32, 2048).
// ---------------------------------------------------------------------------
__global__ __launch_bounds__(256)
void vtrans_kernel(const bf16* __restrict__ vb, bf16* __restrict__ vT)
{
    __shared__ __align__(16) short tile[32][72];
    const int bh = blockIdx.y;
    const int t0 = blockIdx.x * 64;
    const int tid = threadIdx.x;
    const int tl = tid >> 2, c0 = (tid & 3) * 8;
    bf16x8 v = *(const bf16x8*)(vb + ((size_t)bh * TT + t0 + tl) * RP + c0);
    #pragma unroll
    for (int j = 0; j < 8; ++j) tile[c0 + j][tl] = v[j];
    __syncthreads();
    const int c = tid >> 3, tt = (tid & 7) * 8;
    bf16x8 o = *(const bf16x8*)&tile[c][tt];
    *(bf16x8*)(vT + ((size_t)bh * RP + c) * TT + t0 + tt) = o;
}

// ---------------------------------------------------------------------------
// Flash MFMA attention, swapped-QK layout + paired q-tiles.
// Grid (16, 64), 256 thr = 4 waves. Block handles q-tile bx AND q-tile
// 31-bx sequentially -> every block does exactly 33 KV-steps (no tail).
// Each wave owns 16 q-rows of the active tile; KVBLK=64.
// Swapped QK^T: sc[sub] = mfma(K_frag, Q_frag) -> D[s_local=quad*4+r][q=l16];
// lane (quad,l16) holds 16 scores of q-row l16 => m/lsum are per-lane
// scalars; row reduce = in-reg tree + __shfl_xor(16) + __shfl_xor(32).
// Defer-rescale (THR=8): skip oacc rescale while tile max grows < 8.
// P stored [q=l16][s] via 4x ds_write_b64; PV A-frag = contiguous b128 read.
// Output: compact bf16 att (b, t, h*32+c).
// ---------------------------------------------------------------------------
struct __attribute__((aligned(8))) bf4 { bf16 v[4]; };

__global__ __launch_bounds__(256)
void attn_mfma(const bf16* __restrict__ qn, const bf16* __restrict__ kn,
               const bf16* __restrict__ vT, bf16* __restrict__ att)
{
    __shared__ __align__(16) bf16 P_lds[4][16][72];
    const int tid  = threadIdx.x;
    const int wave = tid >> 6, lane = tid & 63;
    const int quad = lane >> 4, l16 = lane & 15;
    const int bx = blockIdx.x;                 // 0..15
    const int bh = blockIdx.y;
    const int b = bh >> 4, h = bh & 15;

    const bf16* knb = kn + (size_t)bh * TT * RP;
    const bf16* vtb = vT + (size_t)bh * RP * TT;

    #pragma unroll 1
    for (int pi = 0; pi < 2; ++pi) {
        const int qt = pi ? (31 - bx) : bx;
        const int qbase = qt * 64 + wave * 16;

        bf16x8 qf = *(const bf16x8*)(qn + ((size_t)bh * TT + qbase + l16) * RP + quad * 8);

        float m = -1e30f, lsum = 0.f;
        f32x4 oacc0 = (f32x4){0.f, 0.f, 0.f, 0.f};
        f32x4 oacc1 = (f32x4){0.f, 0.f, 0.f, 0.f};

        for (int st = 0; st <= qt; ++st) {
            const int s0 = st * 64;

            // ---- swapped QK^T: D[s_local][q] ----
            f32x4 sc[4];
            #pragma unroll
            for (int sub = 0; sub < 4; ++sub) {
                bf16x8 kf = *(const bf16x8*)(knb + (size_t)(s0 + sub * 16 + l16) * RP + quad * 8);
                sc[sub] = __builtin_amdgcn_mfma_f32_16x16x32_bf16(
                    kf, qf, (f32x4){0.f, 0.f, 0.f, 0.f}, 0, 0, 0);
            }

            // ---- causal mask (diagonal tile only) ----
            if (s0 + 63 > qbase) {
                const int qg = qbase + l16;
                #pragma unroll
                for (int sub = 0; sub < 4; ++sub)
                    #pragma unroll
                    for (int r = 0; r < 4; ++r)
                        if (s0 + sub * 16 + quad * 4 + r > qg) sc[sub][r] = -1e30f;
            }

            // ---- tile max for q-row l16: in-reg tree + 2 shuffles ----
            float mx0 = fmaxf(fmaxf(sc[0][0], sc[0][1]), fmaxf(sc[0][2], sc[0][3]));
            float mx1 = fmaxf(fmaxf(sc[1][0], sc[1][1]), fmaxf(sc[1][2], sc[1][3]));
            float mx2 = fmaxf(fmaxf(sc[2][0], sc[2][1]), fmaxf(sc[2][2], sc[2][3]));
            float mx3 = fmaxf(fmaxf(sc[3][0], sc[3][1]), fmaxf(sc[3][2], sc[3][3]));
            float mx  = fmaxf(fmaxf(mx0, mx1), fmaxf(mx2, mx3));
            mx = fmaxf(mx, __shfl_xor(mx, 16, 64));
            mx = fmaxf(mx, __shfl_xor(mx, 32, 64));

            // ---- defer-rescale (THR=8) ----
            if (!__all(mx <= m + 8.f)) {
                const float mnew = fmaxf(m, mx);
                const float scale = __expf(m - mnew);
                lsum *= scale;
                #pragma unroll
                for (int r = 0; r < 4; ++r) {
                    const float scr = __shfl(scale, quad * 20 + r, 64);
                    oacc0[r] *= scr;
                    oacc1[r] *= scr;
                }
                m = mnew;
            }

            // ---- p = exp(sc - m), pack 4 bf16 -> one b64 LDS write / sub ----
            float ps[4];
            #pragma unroll
            for (int sub = 0; sub < 4; ++sub) {
                const float p0 = __expf(sc[sub][0] - m);
                const float p1 = __expf(sc[sub][1] - m);
                const float p2 = __expf(sc[sub][2] - m);
                const float p3 = __expf(sc[sub][3] - m);
                bf4 pk;
                pk.v[0] = __float2bfloat16(p0);
                pk.v[1] = __float2bfloat16(p1);
                pk.v[2] = __float2bfloat16(p2);
                pk.v[3] = __float2bfloat16(p3);
                *(bf4*)&P_lds[wave][l16][sub * 16 + quad * 4] = pk;
                ps[sub] = (p0 + p1) + (p2 + p3);
            }
            float rs = (ps[0] + ps[1]) + (ps[2] + ps[3]);
            rs += __shfl_xor(rs, 16, 64);
            rs += __shfl_xor(rs, 32, 64);
            lsum += rs;

            // ---- PV: P[16q x 64s] @ V^T -> D[q_local][c] ----
            #pragma unroll
            for (int ks = 0; ks < 2; ++ks) {
                bf16x8 pf = *(const bf16x8*)&P_lds[wave][l16][ks * 32 + quad * 8];
                bf16x8 vf0 = *(const bf16x8*)(vtb + (size_t)l16 * TT + s0 + ks * 32 + quad * 8);
                bf16x8 vf1 = *(const bf16x8*)(vtb + (size_t)(16 + l16) * TT + s0 + ks * 32 + quad * 8);
                oacc0 = __builtin_amdgcn_mfma_f32_16x16x32_bf16(pf, vf0, oacc0, 0, 0, 0);
                oacc1 = __builtin_amdgcn_mfma_f32_16x16x32_bf16(pf, vf1, oacc1, 0, 0, 0);
            }
        }

        // ---- epilogue ----
        #pragma unroll
        for (int r = 0; r < 4; ++r) {
            const float ls = __shfl(lsum, quad * 20 + r, 64);
            const float inv = 1.0f / ls;
            const int t = qbase + quad * 4 + r;
            bf16* op = att + ((size_t)(b * TT + t)) * 512 + h * 32;
            op[l16]      = __float2bfloat16(oacc0[r] * inv);
            op[16 + l16] = __float2bfloat16(oacc1[r] * inv);
        }
    }
}

// ---------------------------------------------------------------------------
// Workspace (BYTE offsets from base = d_ws + 64):
//   xb    bf16 [0, 16777216)
//   wqT   bf16 [16777216, 18874368)
//   wkvT  bf16 [18874368, 19136512)
//   qrawb bf16 [19136512, 35913728)
//   kvb   bf16 [33554432, 35651584)     (alias in dead qrawb tail)
//   kvout fp32 [0, 33554432)            (alias over dead xb/wqT/wkvT)
//   att_b bf16 [0, 8388608)             (alias over dead kvout)
//   vTb   bf16 [8388608, 16777216)      (alias over dead kvout)
//   qn    bf16 [35913728, 44302336)
//   kn    bf16 [44302336, 52690944)
//   vb    bf16 [52690944, 61079552)
//   wkwvT bf16 [61079552, 61341696)
//   woT   bf16 [61341696, 62390272)
// ---------------------------------------------------------------------------
extern "C" void kernel_launch(void* const* d_in, const int* in_sizes, int n_in,
                              void* d_out, int out_size, void* d_ws, size_t ws_size,
                              hipStream_t stream)
{
    float* out = (float*)d_out;
    const long long NOUT = (long long)BB * TT * DD;
    const int outgrid = (int)((NOUT + 255) / 256);

    static const long long expect[8] =
        {8388608, 1048576, 131072, 65536, 65536, 1048576, 64, 32};
    if (n_in != 8) {
        sentinel_kernel<<<outgrid, 256, 0, stream>>>(out, 20000.0f + 100.0f * n_in, NOUT);
        return;
    }
    for (int i = 0; i < 8; ++i) {
        if ((long long)in_sizes[i] != expect[i]) {
            sentinel_kernel<<<outgrid, 256, 0, stream>>>(out, 10000.0f + 1000.0f * i, NOUT);
            return;
        }
    }
    if (ws_size < 62914624ULL) {
        sentinel_kernel<<<outgrid, 256, 0, stream>>>(
            out, 30000.0f + (float)(ws_size >> 20), NOUT);
        return;
    }
    if (out_size != 8388608) {
        sentinel_kernel<<<outgrid, 256, 0, stream>>>(
            out, 512.0f * (1.0f + (float)(out_size >> 20)), NOUT);
        return;
    }

    const float* x   = (const float*)d_in[0];
    const float* Wq  = (const float*)d_in[1];
    const float* Wkv = (const float*)d_in[2];
    const float* Wk  = (const float*)d_in[3];
    const float* Wv  = (const float*)d_in[4];
    const float* Wo  = (const float*)d_in[5];
    const float* qg  = (const float*)d_in[6];
    const float* kg  = (const float*)d_in[7];

    char* base = (char*)d_ws + 64;
    bf16*  xb    = (bf16*)(base + 0);
    bf16*  wqT   = (bf16*)(base + 16777216);
    bf16*  wkvT  = (bf16*)(base + 18874368);
    bf16*  qrawb = (bf16*)(base + 19136512);
    bf16*  kvb   = (bf16*)(base + 33554432);
    float* kvout = (float*)(base + 0);
    bf16*  att_b = (bf16*)(base + 0);
    bf16*  vTb   = (bf16*)(base + 8388608);
    bf16*  qn    = (bf16*)(base + 35913728);
    bf16*  kn    = (bf16*)(base + 44302336);
    bf16*  vb    = (bf16*)(base + 52690944);
    bf16*  wkwvT = (bf16*)(base + 61079552);
    bf16*  woT   = (bf16*)(base + 61341696);

    const int BT = BB * TT;                    // 8192

    // 0. converts
    conv_x_kernel<<<outgrid, 256, 0, stream>>>(x, xb, NOUT);
    conv_wT_kernel<<<4096, 256, 0, stream>>>(Wq, wqT, 1024, 1024);
    conv_wT_kernel<<<512, 256, 0, stream>>>(Wkv, wkvT, 1024, 128);
    conv_wkwv_kernel<<<512, 256, 0, stream>>>(Wk, Wv, wkwvT);
    conv_woT_kernel<<<2048, 256, 0, stream>>>(Wo, woT);

    // 1. qrawb = xb @ Wq (MFMA), 8192x1024, K=1024
    gemm_mfma<bf16><<<dim3(8, 64), 256, 0, stream>>>(
        (const short*)xb, (const short*)wqT, qrawb, BT, DD, DD);
    // 2. qn = rmsnorm_64(qrawb)[:32] * 0.125
    qrms_kernel<<<(BT * HH * 64) / 256, 256, 0, stream>>>(qrawb, qg, qn);
    // 3. kvb = xb @ Wkv (MFMA), 8192x128, K=1024
    gemm_mfma<bf16><<<dim3(1, 64), 256, 0, stream>>>(
        (const short*)xb, (const short*)wkvT, kvb, BT, LAT_, DD);
    // 4. kvout = kvb @ [Wk|Wv] (MFMA), 8192x1024, K=128
    gemm_mfma<float><<<dim3(8, 64), 256, 0, stream>>>(
        (const short*)kvb, (const short*)wkwvT, kvout, BT, 2 * 512, LAT_);
    // 5. kn/vb from kvout
    kv_split_kernel<<<(BT * HH * 64) / 256, 256, 0, stream>>>(kvout, kg, kn, vb);
    // 5.5 vT = transpose(vb)
    vtrans_kernel<<<dim3(32, 64), 256, 0, stream>>>(vb, vTb);
    // 6. flash MFMA attention (swapped-QK, paired tiles) -> att_b
    attn_mfma<<<dim3(16, 64), 256, 0, stream>>>(qn, kn, vTb, att_b);
    // 7. out = att_b @ Wo_remap (MFMA), 8192x1024, K=512
    gemm_mfma<float><<<dim3(8, 64), 256, 0, stream>>>(
        (const short*)att_b, (const short*)woT, out, BT, DD, 512);
}

// Round 4
// 339.187 us; speedup vs baseline: 7.6167x; 1.0372x over previous
//
#include <hip/hip_runtime.h>
#include <hip/hip_bf16.h>
#include <math.h>

using bf16 = __hip_bfloat16;
typedef __attribute__((ext_vector_type(8))) short bf16x8;
typedef __attribute__((ext_vector_type(4))) float f32x4;

#define BB   4
#define TT   2048
#define DD   1024
#define HH   16
#define HD_  64
#define LAT_ 128
#define RP   32
#define EPS_ 1e-6f

static __device__ __forceinline__ void stf(float* p, float v) { *p = v; }
static __device__ __forceinline__ void stf(bf16* p, float v) { *p = __float2bfloat16(v); }

// global -> LDS 16B DMA (wave-uniform LDS base + lane*16)
static __device__ __forceinline__ void gl2lds16(const void* g, void* l)
{
    __builtin_amdgcn_global_load_lds(
        (const __attribute__((address_space(1))) void*)g,
        (__attribute__((address_space(3))) void*)l, 16, 0, 0);
}

__global__ __launch_bounds__(256)
void sentinel_kernel(float* __restrict__ out, float val, long long n)
{
    long long i = (long long)blockIdx.x * 256 + threadIdx.x;
    if (i < n) out[i] = val;
}

// ---------------------------------------------------------------------------
// Converters
// ---------------------------------------------------------------------------
__global__ __launch_bounds__(256)
void conv_x_kernel(const float* __restrict__ x, bf16* __restrict__ xb, long long n)
{
    long long i = (long long)blockIdx.x * 256 + threadIdx.x;
    if (i < n) xb[i] = __float2bfloat16(x[i]);
}

// Tiled transpose-convert: W (K x N fp32 row-major) -> WT (N x K bf16).
// Grid (N/64, K/64), 256 thr. Read coalesced float4, LDS 64x64 tile
// (stride 72 shorts -> 16B-aligned rows for b128 reads), write coalesced
// bf16x8. K, N multiples of 64.
__global__ __launch_bounds__(256)
void conv_trans_kernel(const float* __restrict__ W, bf16* __restrict__ WT,
                       int K, int N)
{
    __shared__ __align__(16) bf16 t[64][72];
    const int k0 = blockIdx.y * 64, n0 = blockIdx.x * 64;
    const int tid = threadIdx.x;
    const int r = tid >> 2, c0 = (tid & 3) * 16;       // r: k-local row
    const float* src = W + (size_t)(k0 + r) * N + n0 + c0;
    #pragma unroll
    for (int j = 0; j < 16; j += 4) {
        float4 v = *(const float4*)(src + j);
        t[c0 + j + 0][r] = __float2bfloat16(v.x);
        t[c0 + j + 1][r] = __float2bfloat16(v.y);
        t[c0 + j + 2][r] = __float2bfloat16(v.z);
        t[c0 + j + 3][r] = __float2bfloat16(v.w);
    }
    __syncthreads();
    const int rr = tid >> 2, cc = (tid & 3) * 16;      // rr: n-local row
    bf16* dst = WT + (size_t)(n0 + rr) * K + k0 + cc;
    *(bf16x8*)dst       = *(const bf16x8*)&t[rr][cc];
    *(bf16x8*)(dst + 8) = *(const bf16x8*)&t[rr][cc + 8];
}

// [Wk | Wv] (each 128x512) -> WT (1024 x 128). Small (0.25 MB out).
__global__ __launch_bounds__(256)
void conv_wkwv_kernel(const float* __restrict__ Wk, const float* __restrict__ Wv,
                      bf16* __restrict__ WT)
{
    int idx = blockIdx.x * 256 + threadIdx.x;      // 128*1024
    if (idx >= 128 * 1024) return;
    int k = idx >> 10, n = idx & 1023;
    float v = (n < 512) ? Wk[k * 512 + n] : Wv[k * 512 + (n - 512)];
    WT[(size_t)n * 128 + k] = __float2bfloat16(v);
}

// Wo (1024x1024) -> woT (1024 x 512) tiled transpose with row remap:
// woT[n*512+mm] = Wo[((mm>>5)<<6 | (mm&31))*1024 + n]. Grid (16, 8).
__global__ __launch_bounds__(256)
void conv_woT_kernel(const float* __restrict__ Wo, bf16* __restrict__ WT)
{
    __shared__ __align__(16) bf16 t[64][72];
    const int mm0 = blockIdx.y * 64, n0 = blockIdx.x * 64;
    const int tid = threadIdx.x;
    const int r = tid >> 2, c0 = (tid & 3) * 16;       // r: mm-local
    const int mm = mm0 + r;
    const int row = ((mm >> 5) << 6) | (mm & 31);
    const float* src = Wo + (size_t)row * 1024 + n0 + c0;
    #pragma unroll
    for (int j = 0; j < 16; j += 4) {
        float4 v = *(const float4*)(src + j);
        t[c0 + j + 0][r] = __float2bfloat16(v.x);
        t[c0 + j + 1][r] = __float2bfloat16(v.y);
        t[c0 + j + 2][r] = __float2bfloat16(v.z);
        t[c0 + j + 3][r] = __float2bfloat16(v.w);
    }
    __syncthreads();
    const int rr = tid >> 2, cc = (tid & 3) * 16;      // rr: n-local
    bf16* dst = WT + (size_t)(n0 + rr) * 512 + mm0 + cc;
    *(bf16x8*)dst       = *(const bf16x8*)&t[rr][cc];
    *(bf16x8*)(dst + 8) = *(const bf16x8*)&t[rr][cc + 8];
}

// ---------------------------------------------------------------------------
// MFMA GEMM with global_load_lds staging (m97 pattern). C[M,N] = A @ B,
// A bf16 (M x K) row-major, BT bf16 (N x K) row-major. 128x128 tile, BK=32.
// DMA map: thread t -> LDS flat byte t*16 (rows 0..63) and 4096 + t*16
// (rows 64..127); global row = t>>2, col8 = (t&3)*8. As[128][32] flat byte
// t*16 = row (t>>2), short col (t&3)*8 -> matches.
// Fragment maps (HW-verified): A[m=lane&15][k=quad*8+j],
// BT[n=lane&15][k=quad*8+j], C/D row=quad*4+reg, col=lane&15.
// ---------------------------------------------------------------------------
template <typename OT>
__global__ __launch_bounds__(256)
void gemm_mfma(const short* __restrict__ A, const short* __restrict__ BT,
               OT* __restrict__ C, int M, int N, int K)
{
    __shared__ __align__(16) short As[128][32];
    __shared__ __align__(16) short Bs[128][32];
    const int tid  = threadIdx.x;
    const int wave = tid >> 6, lane = tid & 63;
    const int quad = lane >> 4, l16 = lane & 15;
    const int wr = (wave >> 1) * 64, wc = (wave & 1) * 64;
    const int row0 = blockIdx.y * 128, col0 = blockIdx.x * 128;
    const int srow = tid >> 2, scol = (tid & 3) * 8;

    char* lAs0 = (char*)As + wave * 1024;
    char* lAs1 = (char*)As + 4096 + wave * 1024;
    char* lBs0 = (char*)Bs + wave * 1024;
    char* lBs1 = (char*)Bs + 4096 + wave * 1024;

    f32x4 acc[4][4];
    #pragma unroll
    for (int mt = 0; mt < 4; ++mt)
        #pragma unroll
        for (int nt = 0; nt < 4; ++nt)
            acc[mt][nt] = (f32x4){0.f, 0.f, 0.f, 0.f};

    for (int k0 = 0; k0 < K; k0 += 32) {
        const short* ga = A  + (size_t)(row0 + srow) * K + k0 + scol;
        const short* gb = BT + (size_t)(col0 + srow) * K + k0 + scol;
        __syncthreads();                       // prev tile's reads done
        gl2lds16(ga,                  lAs0);
        gl2lds16(ga + (size_t)64 * K, lAs1);
        gl2lds16(gb,                  lBs0);
        gl2lds16(gb + (size_t)64 * K, lBs1);
        __syncthreads();                       // drains vmcnt -> data ready

        bf16x8 af[4], bfv[4];
        #pragma unroll
        for (int mt = 0; mt < 4; ++mt)
            af[mt] = *(const bf16x8*)&As[wr + mt * 16 + l16][quad * 8];
        #pragma unroll
        for (int nt = 0; nt < 4; ++nt)
            bfv[nt] = *(const bf16x8*)&Bs[wc + nt * 16 + l16][quad * 8];
        #pragma unroll
        for (int mt = 0; mt < 4; ++mt)
            #pragma unroll
            for (int nt = 0; nt < 4; ++nt)
                acc[mt][nt] = __builtin_amdgcn_mfma_f32_16x16x32_bf16(
                    af[mt], bfv[nt], acc[mt][nt], 0, 0, 0);
    }

    #pragma unroll
    for (int mt = 0; mt < 4; ++mt)
        #pragma unroll
        for (int nt = 0; nt < 4; ++nt) {
            const int col = col0 + wc + nt * 16 + l16;
            #pragma unroll
            for (int r = 0; r < 4; ++r) {
                const int row = row0 + wr + mt * 16 + quad * 4 + r;
                stf(C + (size_t)row * N + col, acc[mt][nt][r]);
            }
        }
}

// ---------------------------------------------------------------------------
// Q RMSNorm: rms over 64 head dims; write first 32 dims * 0.125 to
// qn bf16 (b,h,t,32).
// ---------------------------------------------------------------------------
__global__ __launch_bounds__(256)
void qrms_kernel(const bf16* __restrict__ qraw, const float* __restrict__ qg,
                 bf16* __restrict__ qn)
{
    const int gid  = blockIdx.x * 256 + threadIdx.x;
    const int lane = gid & 63;
    const int grp  = gid >> 6;
    const int bt   = grp >> 4;
    const int h    = grp & 15;
    float v = __bfloat162float(qraw[(size_t)bt * DD + h * HD_ + lane]);
    float s = v * v;
    #pragma unroll
    for (int off = 32; off; off >>= 1) s += __shfl_xor(s, off, 64);
    const float inv = 1.0f / sqrtf(s * (1.0f / HD_) + EPS_);
    if (lane < RP) {
        const int b = bt >> 11, t = bt & 2047;
        qn[(((size_t)(b * HH + h)) * TT + t) * RP + lane] =
            __float2bfloat16(qg[lane] * v * inv * 0.125f);
    }
}

// ---------------------------------------------------------------------------
// K RMSNorm (lanes 0..31) + V relayout (lanes 32..63).
// ---------------------------------------------------------------------------
__global__ __launch_bounds__(256)
void kv_split_kernel(const float* __restrict__ kvout, const float* __restrict__ kg,
                     bf16* __restrict__ kn, bf16* __restrict__ vout)
{
    const int gid  = blockIdx.x * 256 + threadIdx.x;
    const int lane = gid & 63;
    const int grp  = gid >> 6;
    const int bt   = grp >> 4;
    const int h    = grp & 15;
    const int b = bt >> 11, t = bt & 2047;
    const size_t dst = (((size_t)(b * HH + h)) * TT + t) * RP;
    if (lane < 32) {
        float v = kvout[(size_t)bt * 1024 + h * 32 + lane];
        float s = v * v;
        #pragma unroll
        for (int off = 16; off; off >>= 1) s += __shfl_xor(s, off, 32);
        const float inv = 1.0f / sqrtf(s * (1.0f / RP) + EPS_);
        kn[dst + lane] = __float2bfloat16(kg[lane] * v * inv);
    } else {
        const int j = lane - 32;
        vout[dst + j] = __float2bfloat16(kvout[(size_t)bt * 1024 + 512 + h * 32 + j]);
    }
}

// ---------------------------------------------------------------------------
// V transpose: vb (bh, t, 32) -> vT (bh, 32, 2048).
// ---------------------------------------------------------------------------
__global__ __launch_bounds__(256)
void vtrans_kernel(const bf16* __restrict__ vb, bf16* __restrict__ vT)
{
    __shared__ __align__(16) short tile[32][72];
    const int bh = blockIdx.y;
    const int t0 = blockIdx.x * 64;
    const int tid = threadIdx.x;
    const int tl = tid >> 2, c0 = (tid & 3) * 8;
    bf16x8 v = *(const bf16x8*)(vb + ((size_t)bh * TT + t0 + tl) * RP + c0);
    #pragma unroll
    for (int j = 0; j < 8; ++j) tile[c0 + j][tl] = v[j];
    __syncthreads();
    const int c = tid >> 3, tt = (tid & 7) * 8;
    bf16x8 o = *(const bf16x8*)&tile[c][tt];
    *(bf16x8*)(vT + ((size_t)bh * RP + c) * TT + t0 + tt) = o;
}

// ---------------------------------------------------------------------------
// Flash MFMA attention, swapped-QK layout + paired q-tiles + XCD swizzle.
// Grid (16, 64), 256 thr = 4 waves. XCD swizzle: remap flat block id so
// all 16 q-tile blocks of one bh share xcd = bh%8 (round-robin model) ->
// per-XCD working set 8 bh x 256 KB = 2 MB < 4 MB L2 (was 16 MB thrash).
// Block handles q-tile bx AND 31-bx -> exactly 33 KV-steps (no tail).
// Swapped QK^T: sc[sub] = mfma(K,Q) -> D[s_local=quad*4+r][q=l16]; lane
// holds 16 scores of q-row l16 => m/lsum per-lane scalars.
// Defer-rescale THR=8. P via 4x ds_write_b64, PV A-frag = b128 read.
// ---------------------------------------------------------------------------
struct __attribute__((aligned(8))) bf4 { bf16 v[4]; };

__global__ __launch_bounds__(256)
void attn_mfma(const bf16* __restrict__ qn, const bf16* __restrict__ kn,
               const bf16* __restrict__ vT, bf16* __restrict__ att)
{
    __shared__ __align__(16) bf16 P_lds[4][16][72];
    const int tid  = threadIdx.x;
    const int wave = tid >> 6, lane = tid & 63;
    const int quad = lane >> 4, l16 = lane & 15;
    // XCD-aware bijective remap of (bx, bh):
    const int f  = (int)(blockIdx.y * 16 + blockIdx.x);   // 0..1023
    const int xr = f & 7, j = f >> 3;                      // j: 0..127
    const int bh = xr + 8 * (j >> 4);                      // bh%8 == xcd
    const int bx = j & 15;                                 // 0..15
    const int b = bh >> 4, h = bh & 15;

    const bf16* knb = kn + (size_t)bh * TT * RP;
    const bf16* vtb = vT + (size_t)bh * RP * TT;

    #pragma unroll 1
    for (int pi = 0; pi < 2; ++pi) {
        const int qt = pi ? (31 - bx) : bx;
        const int qbase = qt * 64 + wave * 16;

        bf16x8 qf = *(const bf16x8*)(qn + ((size_t)bh * TT + qbase + l16) * RP + quad * 8);

        float m = -1e30f, lsum = 0.f;
        f32x4 oacc0 = (f32x4){0.f, 0.f, 0.f, 0.f};
        f32x4 oacc1 = (f32x4){0.f, 0.f, 0.f, 0.f};

        for (int st = 0; st <= qt; ++st) {
            const int s0 = st * 64;

            // ---- swapped QK^T: D[s_local][q] ----
            f32x4 sc[4];
            #pragma unroll
            for (int sub = 0; sub < 4; ++sub) {
                bf16x8 kf = *(const bf16x8*)(knb + (size_t)(s0 + sub * 16 + l16) * RP + quad * 8);
                sc[sub] = __builtin_amdgcn_mfma_f32_16x16x32_bf16(
                    kf, qf, (f32x4){0.f, 0.f, 0.f, 0.f}, 0, 0, 0);
            }

            // ---- causal mask (diagonal tile only) ----
            if (s0 + 63 > qbase) {
                const int qg = qbase + l16;
                #pragma unroll
                for (int sub = 0; sub < 4; ++sub)
                    #pragma unroll
                    for (int r = 0; r < 4; ++r)
                        if (s0 + sub * 16 + quad * 4 + r > qg) sc[sub][r] = -1e30f;
            }

            // ---- tile max for q-row l16: in-reg tree + 2 shuffles ----
            float mx0 = fmaxf(fmaxf(sc[0][0], sc[0][1]), fmaxf(sc[0][2], sc[0][3]));
            float mx1 = fmaxf(fmaxf(sc[1][0], sc[1][1]), fmaxf(sc[1][2], sc[1][3]));
            float mx2 = fmaxf(fmaxf(sc[2][0], sc[2][1]), fmaxf(sc[2][2], sc[2][3]));
            float mx3 = fmaxf(fmaxf(sc[3][0], sc[3][1]), fmaxf(sc[3][2], sc[3][3]));
            float mx  = fmaxf(fmaxf(mx0, mx1), fmaxf(mx2, mx3));
            mx = fmaxf(mx, __shfl_xor(mx, 16, 64));
            mx = fmaxf(mx, __shfl_xor(mx, 32, 64));

            // ---- defer-rescale (THR=8) ----
            if (!__all(mx <= m + 8.f)) {
                const float mnew = fmaxf(m, mx);
                const float scale = __expf(m - mnew);
                lsum *= scale;
                #pragma unroll
                for (int r = 0; r < 4; ++r) {
                    const float scr = __shfl(scale, quad * 20 + r, 64);
                    oacc0[r] *= scr;
                    oacc1[r] *= scr;
                }
                m = mnew;
            }

            // ---- p = exp(sc - m), pack 4 bf16 -> one b64 LDS write / sub ----
            float ps[4];
            #pragma unroll
            for (int sub = 0; sub < 4; ++sub) {
                const float p0 = __expf(sc[sub][0] - m);
                const float p1 = __expf(sc[sub][1] - m);
                const float p2 = __expf(sc[sub][2] - m);
                const float p3 = __expf(sc[sub][3] - m);
                bf4 pk;
                pk.v[0] = __float2bfloat16(p0);
                pk.v[1] = __float2bfloat16(p1);
                pk.v[2] = __float2bfloat16(p2);
                pk.v[3] = __float2bfloat16(p3);
                *(bf4*)&P_lds[wave][l16][sub * 16 + quad * 4] = pk;
                ps[sub] = (p0 + p1) + (p2 + p3);
            }
            float rs = (ps[0] + ps[1]) + (ps[2] + ps[3]);
            rs += __shfl_xor(rs, 16, 64);
            rs += __shfl_xor(rs, 32, 64);
            lsum += rs;

            // ---- PV: P[16q x 64s] @ V^T -> D[q_local][c] ----
            #pragma unroll
            for (int ks = 0; ks < 2; ++ks) {
                bf16x8 pf = *(const bf16x8*)&P_lds[wave][l16][ks * 32 + quad * 8];
                bf16x8 vf0 = *(const bf16x8*)(vtb + (size_t)l16 * TT + s0 + ks * 32 + quad * 8);
                bf16x8 vf1 = *(const bf16x8*)(vtb + (size_t)(16 + l16) * TT + s0 + ks * 32 + quad * 8);
                oacc0 = __builtin_amdgcn_mfma_f32_16x16x32_bf16(pf, vf0, oacc0, 0, 0, 0);
                oacc1 = __builtin_amdgcn_mfma_f32_16x16x32_bf16(pf, vf1, oacc1, 0, 0, 0);
            }
        }

        // ---- epilogue ----
        #pragma unroll
        for (int r = 0; r < 4; ++r) {
            const float ls = __shfl(lsum, quad * 20 + r, 64);
            const float inv = 1.0f / ls;
            const int t = qbase + quad * 4 + r;
            bf16* op = att + ((size_t)(b * TT + t)) * 512 + h * 32;
            op[l16]      = __float2bfloat16(oacc0[r] * inv);
            op[16 + l16] = __float2bfloat16(oacc1[r] * inv);
        }
    }
}

// ---------------------------------------------------------------------------
// Workspace (BYTE offsets from base = d_ws + 64):
//   xb    bf16 [0, 16777216)
//   wqT   bf16 [16777216, 18874368)
//   wkvT  bf16 [18874368, 19136512)
//   qrawb bf16 [19136512, 35913728)
//   kvb   bf16 [33554432, 35651584)     (alias in dead qrawb tail)
//   kvout fp32 [0, 33554432)            (alias over dead xb/wqT/wkvT)
//   att_b bf16 [0, 8388608)             (alias over dead kvout)
//   vTb   bf16 [8388608, 16777216)      (alias over dead kvout)
//   qn    bf16 [35913728, 44302336)
//   kn    bf16 [44302336, 52690944)
//   vb    bf16 [52690944, 61079552)
//   wkwvT bf16 [61079552, 61341696)
//   woT   bf16 [61341696, 62390272)
// ---------------------------------------------------------------------------
extern "C" void kernel_launch(void* const* d_in, const int* in_sizes, int n_in,
                              void* d_out, int out_size, void* d_ws, size_t ws_size,
                              hipStream_t stream)
{
    float* out = (float*)d_out;
    const long long NOUT = (long long)BB * TT * DD;
    const int outgrid = (int)((NOUT + 255) / 256);

    static const long long expect[8] =
        {8388608, 1048576, 131072, 65536, 65536, 1048576, 64, 32};
    if (n_in != 8) {
        sentinel_kernel<<<outgrid, 256, 0, stream>>>(out, 20000.0f + 100.0f * n_in, NOUT);
        return;
    }
    for (int i = 0; i < 8; ++i) {
        if ((long long)in_sizes[i] != expect[i]) {
            sentinel_kernel<<<outgrid, 256, 0, stream>>>(out, 10000.0f + 1000.0f * i, NOUT);
            return;
        }
    }
    if (ws_size < 62914624ULL) {
        sentinel_kernel<<<outgrid, 256, 0, stream>>>(
            out, 30000.0f + (float)(ws_size >> 20), NOUT);
        return;
    }
    if (out_size != 8388608) {
        sentinel_kernel<<<outgrid, 256, 0, stream>>>(
            out, 512.0f * (1.0f + (float)(out_size >> 20)), NOUT);
        return;
    }

    const float* x   = (const float*)d_in[0];
    const float* Wq  = (const float*)d_in[1];
    const float* Wkv = (const float*)d_in[2];
    const float* Wk  = (const float*)d_in[3];
    const float* Wv  = (const float*)d_in[4];
    const float* Wo  = (const float*)d_in[5];
    const float* qg  = (const float*)d_in[6];
    const float* kg  = (const float*)d_in[7];

    char* base = (char*)d_ws + 64;
    bf16*  xb    = (bf16*)(base + 0);
    bf16*  wqT   = (bf16*)(base + 16777216);
    bf16*  wkvT  = (bf16*)(base + 18874368);
    bf16*  qrawb = (bf16*)(base + 19136512);
    bf16*  kvb   = (bf16*)(base + 33554432);
    float* kvout = (float*)(base + 0);
    bf16*  att_b = (bf16*)(base + 0);
    bf16*  vTb   = (bf16*)(base + 8388608);
    bf16*  qn    = (bf16*)(base + 35913728);
    bf16*  kn    = (bf16*)(base + 44302336);
    bf16*  vb    = (bf16*)(base + 52690944);
    bf16*  wkwvT = (bf16*)(base + 61079552);
    bf16*  woT   = (bf16*)(base + 61341696);

    const int BT = BB * TT;                    // 8192

    // 0. converts (tiled transposes for the big weights)
    conv_x_kernel<<<outgrid, 256, 0, stream>>>(x, xb, NOUT);
    conv_trans_kernel<<<dim3(16, 16), 256, 0, stream>>>(Wq, wqT, 1024, 1024);
    conv_trans_kernel<<<dim3(2, 16), 256, 0, stream>>>(Wkv, wkvT, 1024, 128);
    conv_wkwv_kernel<<<512, 256, 0, stream>>>(Wk, Wv, wkwvT);
    conv_woT_kernel<<<dim3(16, 8), 256, 0, stream>>>(Wo, woT);

    // 1. qrawb = xb @ Wq (MFMA), 8192x1024, K=1024
    gemm_mfma<bf16><<<dim3(8, 64), 256, 0, stream>>>(
        (const short*)xb, (const short*)wqT, qrawb, BT, DD, DD);
    // 2. qn = rmsnorm_64(qrawb)[:32] * 0.125
    qrms_kernel<<<(BT * HH * 64) / 256, 256, 0, stream>>>(qrawb, qg, qn);
    // 3. kvb = xb @ Wkv (MFMA), 8192x128, K=1024
    gemm_mfma<bf16><<<dim3(1, 64), 256, 0, stream>>>(
        (const short*)xb, (const short*)wkvT, kvb, BT, LAT_, DD);
    // 4. kvout = kvb @ [Wk|Wv] (MFMA), 8192x1024, K=128
    gemm_mfma<float><<<dim3(8, 64), 256, 0, stream>>>(
        (const short*)kvb, (const short*)wkwvT, kvout, BT, 2 * 512, LAT_);
    // 5. kn/vb from kvout
    kv_split_kernel<<<(BT * HH * 64) / 256, 256, 0, stream>>>(kvout, kg, kn, vb);
    // 5.5 vT = transpose(vb)
    vtrans_kernel<<<dim3(32, 64), 256, 0, stream>>>(vb, vTb);
    // 6. flash MFMA attention (swapped-QK, paired tiles, XCD swizzle)
    attn_mfma<<<dim3(16, 64), 256, 0, stream>>>(qn, kn, vTb, att_b);
    // 7. out = att_b @ Wo_remap (MFMA), 8192x1024, K=512
    gemm_mfma<float><<<dim3(8, 64), 256, 0, stream>>>(
        (const short*)att_b, (const short*)woT, out, BT, DD, 512);
}

// Round 5
// 291.560 us; speedup vs baseline: 8.8610x; 1.1634x over previous
//
#include <hip/hip_runtime.h>
#include <hip/hip_bf16.h>
#include <math.h>

using bf16 = __hip_bfloat16;
typedef __attribute__((ext_vector_type(8))) short bf16x8;
typedef __attribute__((ext_vector_type(4))) float f32x4;

#define BB   4
#define TT   2048
#define DD   1024
#define HH   16
#define HD_  64
#define LAT_ 128
#define RP   32
#define EPS_ 1e-6f

static __device__ __forceinline__ void stf(float* p, float v) { *p = v; }
static __device__ __forceinline__ void stf(bf16* p, float v) { *p = __float2bfloat16(v); }

// global -> LDS 16B DMA (wave-uniform LDS base + lane*16)
static __device__ __forceinline__ void gl2lds16(const void* g, void* l)
{
    __builtin_amdgcn_global_load_lds(
        (const __attribute__((address_space(1))) void*)g,
        (__attribute__((address_space(3))) void*)l, 16, 0, 0);
}

__global__ __launch_bounds__(256)
void sentinel_kernel(float* __restrict__ out, float val, long long n)
{
    long long i = (long long)blockIdx.x * 256 + threadIdx.x;
    if (i < n) out[i] = val;
}

// ---------------------------------------------------------------------------
// Converters
// ---------------------------------------------------------------------------
__global__ __launch_bounds__(256)
void conv_x_kernel(const float* __restrict__ x, bf16* __restrict__ xb, long long n)
{
    long long i = (long long)blockIdx.x * 256 + threadIdx.x;
    if (i < n) xb[i] = __float2bfloat16(x[i]);
}

// Tiled transpose-convert: W (K x N fp32 row-major) -> WT (N x K bf16).
__global__ __launch_bounds__(256)
void conv_trans_kernel(const float* __restrict__ W, bf16* __restrict__ WT,
                       int K, int N)
{
    __shared__ __align__(16) bf16 t[64][72];
    const int k0 = blockIdx.y * 64, n0 = blockIdx.x * 64;
    const int tid = threadIdx.x;
    const int r = tid >> 2, c0 = (tid & 3) * 16;
    const float* src = W + (size_t)(k0 + r) * N + n0 + c0;
    #pragma unroll
    for (int j = 0; j < 16; j += 4) {
        float4 v = *(const float4*)(src + j);
        t[c0 + j + 0][r] = __float2bfloat16(v.x);
        t[c0 + j + 1][r] = __float2bfloat16(v.y);
        t[c0 + j + 2][r] = __float2bfloat16(v.z);
        t[c0 + j + 3][r] = __float2bfloat16(v.w);
    }
    __syncthreads();
    const int rr = tid >> 2, cc = (tid & 3) * 16;
    bf16* dst = WT + (size_t)(n0 + rr) * K + k0 + cc;
    *(bf16x8*)dst       = *(const bf16x8*)&t[rr][cc];
    *(bf16x8*)(dst + 8) = *(const bf16x8*)&t[rr][cc + 8];
}

// [Wk | Wv] (each 128x512) -> WT (1024 x 128).
__global__ __launch_bounds__(256)
void conv_wkwv_kernel(const float* __restrict__ Wk, const float* __restrict__ Wv,
                      bf16* __restrict__ WT)
{
    int idx = blockIdx.x * 256 + threadIdx.x;      // 128*1024
    if (idx >= 128 * 1024) return;
    int k = idx >> 10, n = idx & 1023;
    float v = (n < 512) ? Wk[k * 512 + n] : Wv[k * 512 + (n - 512)];
    WT[(size_t)n * 128 + k] = __float2bfloat16(v);
}

// Wo (1024x1024) -> woT (1024 x 512) tiled transpose with row remap.
__global__ __launch_bounds__(256)
void conv_woT_kernel(const float* __restrict__ Wo, bf16* __restrict__ WT)
{
    __shared__ __align__(16) bf16 t[64][72];
    const int mm0 = blockIdx.y * 64, n0 = blockIdx.x * 64;
    const int tid = threadIdx.x;
    const int r = tid >> 2, c0 = (tid & 3) * 16;
    const int mm = mm0 + r;
    const int row = ((mm >> 5) << 6) | (mm & 31);
    const float* src = Wo + (size_t)row * 1024 + n0 + c0;
    #pragma unroll
    for (int j = 0; j < 16; j += 4) {
        float4 v = *(const float4*)(src + j);
        t[c0 + j + 0][r] = __float2bfloat16(v.x);
        t[c0 + j + 1][r] = __float2bfloat16(v.y);
        t[c0 + j + 2][r] = __float2bfloat16(v.z);
        t[c0 + j + 3][r] = __float2bfloat16(v.w);
    }
    __syncthreads();
    const int rr = tid >> 2, cc = (tid & 3) * 16;
    bf16* dst = WT + (size_t)(n0 + rr) * 512 + mm0 + cc;
    *(bf16x8*)dst       = *(const bf16x8*)&t[rr][cc];
    *(bf16x8*)(dst + 8) = *(const bf16x8*)&t[rr][cc + 8];
}

// ---------------------------------------------------------------------------
// MFMA GEMM with global_load_lds staging. C[M,N] = A @ B, A bf16 (M x K)
// row-major, BT bf16 (N x K) row-major. 128x128 tile, BK=32.
// Fragment maps (HW-verified): A[m=lane&15][k=quad*8+j],
// BT[n=lane&15][k=quad*8+j], C/D row=quad*4+reg, col=lane&15.
// ---------------------------------------------------------------------------
#define GEMM_PROLOG_128 \
    __shared__ __align__(16) short As[128][32]; \
    __shared__ __align__(16) short Bs[128][32]; \
    const int tid  = threadIdx.x; \
    const int wave = tid >> 6, lane = tid & 63; \
    const int quad = lane >> 4, l16 = lane & 15; \
    const int wr = (wave >> 1) * 64, wc = (wave & 1) * 64; \
    const int row0 = blockIdx.y * 128, col0 = blockIdx.x * 128; \
    const int srow = tid >> 2, scol = (tid & 3) * 8; \
    char* lAs0 = (char*)As + wave * 1024; \
    char* lAs1 = (char*)As + 4096 + wave * 1024; \
    char* lBs0 = (char*)Bs + wave * 1024; \
    char* lBs1 = (char*)Bs + 4096 + wave * 1024; \
    f32x4 acc[4][4]; \
    _Pragma("unroll") \
    for (int mt = 0; mt < 4; ++mt) \
        _Pragma("unroll") \
        for (int nt = 0; nt < 4; ++nt) \
            acc[mt][nt] = (f32x4){0.f, 0.f, 0.f, 0.f}; \
    for (int k0 = 0; k0 < K; k0 += 32) { \
        const short* ga = A  + (size_t)(row0 + srow) * K + k0 + scol; \
        const short* gb = BT + (size_t)(col0 + srow) * K + k0 + scol; \
        __syncthreads(); \
        gl2lds16(ga,                  lAs0); \
        gl2lds16(ga + (size_t)64 * K, lAs1); \
        gl2lds16(gb,                  lBs0); \
        gl2lds16(gb + (size_t)64 * K, lBs1); \
        __syncthreads(); \
        bf16x8 af[4], bfv[4]; \
        _Pragma("unroll") \
        for (int mt = 0; mt < 4; ++mt) \
            af[mt] = *(const bf16x8*)&As[wr + mt * 16 + l16][quad * 8]; \
        _Pragma("unroll") \
        for (int nt = 0; nt < 4; ++nt) \
            bfv[nt] = *(const bf16x8*)&Bs[wc + nt * 16 + l16][quad * 8]; \
        _Pragma("unroll") \
        for (int mt = 0; mt < 4; ++mt) \
            _Pragma("unroll") \
            for (int nt = 0; nt < 4; ++nt) \
                acc[mt][nt] = __builtin_amdgcn_mfma_f32_16x16x32_bf16( \
                    af[mt], bfv[nt], acc[mt][nt], 0, 0, 0); \
    }

template <typename OT>
__global__ __launch_bounds__(256)
void gemm_mfma(const short* __restrict__ A, const short* __restrict__ BT,
               OT* __restrict__ C, int M, int N, int K)
{
    GEMM_PROLOG_128
    #pragma unroll
    for (int mt = 0; mt < 4; ++mt)
        #pragma unroll
        for (int nt = 0; nt < 4; ++nt) {
            const int col = col0 + wc + nt * 16 + l16;
            #pragma unroll
            for (int r = 0; r < 4; ++r) {
                const int row = row0 + wr + mt * 16 + quad * 4 + r;
                stf(C + (size_t)row * N + col, acc[mt][nt][r]);
            }
        }
}

// ---------------------------------------------------------------------------
// GEMM1 + fused Q-RMSNorm epilogue. Computes qraw tile, then per output row
// (quad*4+r) reduces sum-of-squares over the 64-dim head (4 nt x 16 l16;
// head is wave-uniform: h = (col0+wc)/64), writes first 32 dims scaled by
// qg * inv_rms * 0.125 to qn (b,h,t,32). qraw never materialized.
// ---------------------------------------------------------------------------
__global__ __launch_bounds__(256)
void gemm_qrms(const short* __restrict__ A, const short* __restrict__ BT,
               bf16* __restrict__ qn, const float* __restrict__ qg,
               int M, int N, int K)
{
    GEMM_PROLOG_128
    const int h = (col0 + wc) >> 6;
    const float g0 = qg[l16], g1 = qg[16 + l16];
    #pragma unroll
    for (int mt = 0; mt < 4; ++mt) {
        float ss[4];
        #pragma unroll
        for (int r = 0; r < 4; ++r)
            ss[r] = acc[mt][0][r] * acc[mt][0][r] + acc[mt][1][r] * acc[mt][1][r]
                  + acc[mt][2][r] * acc[mt][2][r] + acc[mt][3][r] * acc[mt][3][r];
        #pragma unroll
        for (int off = 1; off < 16; off <<= 1)
            #pragma unroll
            for (int r = 0; r < 4; ++r) ss[r] += __shfl_xor(ss[r], off, 64);
        #pragma unroll
        for (int r = 0; r < 4; ++r) {
            const float inv = 0.125f / sqrtf(ss[r] * (1.0f / HD_) + EPS_);
            const int row = row0 + wr + mt * 16 + quad * 4 + r;
            const int b = row >> 11, t = row & 2047;
            bf16* op = qn + (((size_t)(b * HH + h)) * TT + t) * RP;
            op[l16]      = __float2bfloat16(g0 * acc[mt][0][r] * inv);
            op[16 + l16] = __float2bfloat16(g1 * acc[mt][1][r] * inv);
        }
    }
}

// ---------------------------------------------------------------------------
// GEMM4 + fused K-RMSNorm / V-split epilogue. Block cols are all-K
// (col0 < 512) or all-V. K path: per row, two 32-dim groups (nt pairs
// {0,1},{2,3}); rms reduce over 16 lanes; write kn bf16 (b,h,t,32) with kg.
// V path: write vb bf16 (b,h,t,32) directly. kvout never materialized.
// ---------------------------------------------------------------------------
__global__ __launch_bounds__(256)
void gemm_kv(const short* __restrict__ A, const short* __restrict__ BT,
             bf16* __restrict__ kn, bf16* __restrict__ vb,
             const float* __restrict__ kg, int M, int N, int K)
{
    GEMM_PROLOG_128
    const int colbase = col0 + wc;
    if (colbase < 512) {                        // K-RMS path
        const int h0 = colbase >> 5;            // groups h0, h0+1
        const float g0 = kg[l16], g1 = kg[16 + l16];
        #pragma unroll
        for (int mt = 0; mt < 4; ++mt) {
            float s0[4], s1[4];
            #pragma unroll
            for (int r = 0; r < 4; ++r) {
                s0[r] = acc[mt][0][r] * acc[mt][0][r] + acc[mt][1][r] * acc[mt][1][r];
                s1[r] = acc[mt][2][r] * acc[mt][2][r] + acc[mt][3][r] * acc[mt][3][r];
            }
            #pragma unroll
            for (int off = 1; off < 16; off <<= 1)
                #pragma unroll
                for (int r = 0; r < 4; ++r) {
                    s0[r] += __shfl_xor(s0[r], off, 64);
                    s1[r] += __shfl_xor(s1[r], off, 64);
                }
            #pragma unroll
            for (int r = 0; r < 4; ++r) {
                const float i0 = 1.0f / sqrtf(s0[r] * (1.0f / RP) + EPS_);
                const float i1 = 1.0f / sqrtf(s1[r] * (1.0f / RP) + EPS_);
                const int row = row0 + wr + mt * 16 + quad * 4 + r;
                const int b = row >> 11, t = row & 2047;
                bf16* op0 = kn + (((size_t)(b * HH + h0)) * TT + t) * RP;
                bf16* op1 = kn + (((size_t)(b * HH + h0 + 1)) * TT + t) * RP;
                op0[l16]      = __float2bfloat16(g0 * acc[mt][0][r] * i0);
                op0[16 + l16] = __float2bfloat16(g1 * acc[mt][1][r] * i0);
                op1[l16]      = __float2bfloat16(g0 * acc[mt][2][r] * i1);
                op1[16 + l16] = __float2bfloat16(g1 * acc[mt][3][r] * i1);
            }
        }
    } else {                                     // V path
        const int h0 = (colbase - 512) >> 5;
        #pragma unroll
        for (int mt = 0; mt < 4; ++mt)
            #pragma unroll
            for (int r = 0; r < 4; ++r) {
                const int row = row0 + wr + mt * 16 + quad * 4 + r;
                const int b = row >> 11, t = row & 2047;
                bf16* op0 = vb + (((size_t)(b * HH + h0)) * TT + t) * RP;
                bf16* op1 = vb + (((size_t)(b * HH + h0 + 1)) * TT + t) * RP;
                op0[l16]      = __float2bfloat16(acc[mt][0][r]);
                op0[16 + l16] = __float2bfloat16(acc[mt][1][r]);
                op1[l16]      = __float2bfloat16(acc[mt][2][r]);
                op1[16 + l16] = __float2bfloat16(acc[mt][3][r]);
            }
    }
}

// ---------------------------------------------------------------------------
// 64x128-tile GEMM (for M-heavy, N=128 gemm3: doubles block count to 128).
// 4 waves, each 32x64: wr=(wave>>1)*32, wc=(wave&1)*64, acc[2][4].
// ---------------------------------------------------------------------------
__global__ __launch_bounds__(256)
void gemm_k64(const short* __restrict__ A, const short* __restrict__ BT,
              bf16* __restrict__ C, int M, int N, int K)
{
    __shared__ __align__(16) short As[64][32];
    __shared__ __align__(16) short Bs[128][32];
    const int tid  = threadIdx.x;
    const int wave = tid >> 6, lane = tid & 63;
    const int quad = lane >> 4, l16 = lane & 15;
    const int wr = (wave >> 1) * 32, wc = (wave & 1) * 64;
    const int row0 = blockIdx.y * 64, col0 = blockIdx.x * 128;
    const int srow = tid >> 2, scol = (tid & 3) * 8;

    char* lAs  = (char*)As + wave * 1024;
    char* lBs0 = (char*)Bs + wave * 1024;
    char* lBs1 = (char*)Bs + 4096 + wave * 1024;

    f32x4 acc[2][4];
    #pragma unroll
    for (int mt = 0; mt < 2; ++mt)
        #pragma unroll
        for (int nt = 0; nt < 4; ++nt)
            acc[mt][nt] = (f32x4){0.f, 0.f, 0.f, 0.f};

    for (int k0 = 0; k0 < K; k0 += 32) {
        const short* ga = A  + (size_t)(row0 + srow) * K + k0 + scol;
        const short* gb = BT + (size_t)(col0 + srow) * K + k0 + scol;
        __syncthreads();
        gl2lds16(ga,                  lAs);
        gl2lds16(gb,                  lBs0);
        gl2lds16(gb + (size_t)64 * K, lBs1);
        __syncthreads();

        bf16x8 af[2], bfv[4];
        #pragma unroll
        for (int mt = 0; mt < 2; ++mt)
            af[mt] = *(const bf16x8*)&As[wr + mt * 16 + l16][quad * 8];
        #pragma unroll
        for (int nt = 0; nt < 4; ++nt)
            bfv[nt] = *(const bf16x8*)&Bs[wc + nt * 16 + l16][quad * 8];
        #pragma unroll
        for (int mt = 0; mt < 2; ++mt)
            #pragma unroll
            for (int nt = 0; nt < 4; ++nt)
                acc[mt][nt] = __builtin_amdgcn_mfma_f32_16x16x32_bf16(
                    af[mt], bfv[nt], acc[mt][nt], 0, 0, 0);
    }

    #pragma unroll
    for (int mt = 0; mt < 2; ++mt)
        #pragma unroll
        for (int nt = 0; nt < 4; ++nt) {
            const int col = col0 + wc + nt * 16 + l16;
            #pragma unroll
            for (int r = 0; r < 4; ++r) {
                const int row = row0 + wr + mt * 16 + quad * 4 + r;
                C[(size_t)row * N + col] = __float2bfloat16(acc[mt][nt][r]);
            }
        }
}

// ---------------------------------------------------------------------------
// V transpose: vb (bh, t, 32) -> vT (bh, 32, 2048).
// ---------------------------------------------------------------------------
__global__ __launch_bounds__(256)
void vtrans_kernel(const bf16* __restrict__ vb, bf16* __restrict__ vT)
{
    __shared__ __align__(16) short tile[32][72];
    const int bh = blockIdx.y;
    const int t0 = blockIdx.x * 64;
    const int tid = threadIdx.x;
    const int tl = tid >> 2, c0 = (tid & 3) * 8;
    bf16x8 v = *(const bf16x8*)(vb + ((size_t)bh * TT + t0 + tl) * RP + c0);
    #pragma unroll
    for (int j = 0; j < 8; ++j) tile[c0 + j][tl] = v[j];
    __syncthreads();
    const int c = tid >> 3, tt = (tid & 7) * 8;
    bf16x8 o = *(const bf16x8*)&tile[c][tt];
    *(bf16x8*)(vT + ((size_t)bh * RP + c) * TT + t0 + tt) = o;
}

// ---------------------------------------------------------------------------
// Flash MFMA attention, swapped-QK + paired q-tiles + XCD swizzle.
// NO online max: scores bounded (|q.k/8| <= 5.66 by RMS-norm), so
// p = exp(score) directly (<= e^5.66 ~ 287, bf16-safe). Softmax divides by
// the per-row sum at the end -> mathematically identical. This removes ALL
// cross-lane ops from the main loop; lsum is a per-lane partial reduced
// once in the epilogue.
// ---------------------------------------------------------------------------
struct __attribute__((aligned(8))) bf4 { bf16 v[4]; };

__global__ __launch_bounds__(256)
void attn_mfma(const bf16* __restrict__ qn, const bf16* __restrict__ kn,
               const bf16* __restrict__ vT, bf16* __restrict__ att)
{
    __shared__ __align__(16) bf16 P_lds[4][16][72];
    const int tid  = threadIdx.x;
    const int wave = tid >> 6, lane = tid & 63;
    const int quad = lane >> 4, l16 = lane & 15;
    // XCD-aware bijective remap of (bx, bh):
    const int f  = (int)(blockIdx.y * 16 + blockIdx.x);   // 0..1023
    const int xr = f & 7, j = f >> 3;                      // j: 0..127
    const int bh = xr + 8 * (j >> 4);                      // bh%8 == xcd
    const int bx = j & 15;                                 // 0..15
    const int b = bh >> 4, h = bh & 15;

    const bf16* knb = kn + (size_t)bh * TT * RP;
    const bf16* vtb = vT + (size_t)bh * RP * TT;

    #pragma unroll 1
    for (int pi = 0; pi < 2; ++pi) {
        const int qt = pi ? (31 - bx) : bx;
        const int qbase = qt * 64 + wave * 16;

        bf16x8 qf = *(const bf16x8*)(qn + ((size_t)bh * TT + qbase + l16) * RP + quad * 8);

        float lsum = 0.f;
        f32x4 oacc0 = (f32x4){0.f, 0.f, 0.f, 0.f};
        f32x4 oacc1 = (f32x4){0.f, 0.f, 0.f, 0.f};

        for (int st = 0; st <= qt; ++st) {
            const int s0 = st * 64;

            // ---- swapped QK^T: D[s_local=quad*4+r][q=l16] ----
            f32x4 sc[4];
            #pragma unroll
            for (int sub = 0; sub < 4; ++sub) {
                bf16x8 kf = *(const bf16x8*)(knb + (size_t)(s0 + sub * 16 + l16) * RP + quad * 8);
                sc[sub] = __builtin_amdgcn_mfma_f32_16x16x32_bf16(
                    kf, qf, (f32x4){0.f, 0.f, 0.f, 0.f}, 0, 0, 0);
            }

            // ---- causal mask (diagonal tile only) ----
            if (s0 + 63 > qbase) {
                const int qg = qbase + l16;
                #pragma unroll
                for (int sub = 0; sub < 4; ++sub)
                    #pragma unroll
                    for (int r = 0; r < 4; ++r)
                        if (s0 + sub * 16 + quad * 4 + r > qg) sc[sub][r] = -1e30f;
            }

            // ---- p = exp(sc), pack -> LDS; per-lane partial sum ----
            #pragma unroll
            for (int sub = 0; sub < 4; ++sub) {
                const float p0 = __expf(sc[sub][0]);
                const float p1 = __expf(sc[sub][1]);
                const float p2 = __expf(sc[sub][2]);
                const float p3 = __expf(sc[sub][3]);
                bf4 pk;
                pk.v[0] = __float2bfloat16(p0);
                pk.v[1] = __float2bfloat16(p1);
                pk.v[2] = __float2bfloat16(p2);
                pk.v[3] = __float2bfloat16(p3);
                *(bf4*)&P_lds[wave][l16][sub * 16 + quad * 4] = pk;
                lsum += (p0 + p1) + (p2 + p3);
            }

            // ---- PV: P[16q x 64s] @ V^T -> D[q_local][c] ----
            #pragma unroll
            for (int ks = 0; ks < 2; ++ks) {
                bf16x8 pf = *(const bf16x8*)&P_lds[wave][l16][ks * 32 + quad * 8];
                bf16x8 vf0 = *(const bf16x8*)(vtb + (size_t)l16 * TT + s0 + ks * 32 + quad * 8);
                bf16x8 vf1 = *(const bf16x8*)(vtb + (size_t)(16 + l16) * TT + s0 + ks * 32 + quad * 8);
                oacc0 = __builtin_amdgcn_mfma_f32_16x16x32_bf16(pf, vf0, oacc0, 0, 0, 0);
                oacc1 = __builtin_amdgcn_mfma_f32_16x16x32_bf16(pf, vf1, oacc1, 0, 0, 0);
            }
        }

        // ---- epilogue: reduce lsum across quads once ----
        lsum += __shfl_xor(lsum, 16, 64);
        lsum += __shfl_xor(lsum, 32, 64);
        #pragma unroll
        for (int r = 0; r < 4; ++r) {
            const float ls = __shfl(lsum, quad * 20 + r, 64);
            const float inv = 1.0f / ls;
            const int t = qbase + quad * 4 + r;
            bf16* op = att + ((size_t)(b * TT + t)) * 512 + h * 32;
            op[l16]      = __float2bfloat16(oacc0[r] * inv);
            op[16 + l16] = __float2bfloat16(oacc1[r] * inv);
        }
    }
}

// ---------------------------------------------------------------------------
// Workspace (BYTE offsets from base = d_ws + 64):
//   xb    bf16 [0, 16777216)            (dead after gemm_k64)
//   wqT   bf16 [16777216, 18874368)     (dead after gemm_qrms)
//   wkvT  bf16 [18874368, 19136512)     (dead after gemm_k64)
//   kvb   bf16 [19136512, 21233664)     (dead after gemm_kv)
//   att_b bf16 [0, 8388608)             (alias over dead xb)
//   vTb   bf16 [8388608, 16777216)      (alias over dead xb)
//   qn    bf16 [35913728, 44302336)
//   kn    bf16 [44302336, 52690944)
//   vb    bf16 [52690944, 61079552)
//   wkwvT bf16 [61079552, 61341696)
//   woT   bf16 [61341696, 62390272)
// ---------------------------------------------------------------------------
extern "C" void kernel_launch(void* const* d_in, const int* in_sizes, int n_in,
                              void* d_out, int out_size, void* d_ws, size_t ws_size,
                              hipStream_t stream)
{
    float* out = (float*)d_out;
    const long long NOUT = (long long)BB * TT * DD;
    const int outgrid = (int)((NOUT + 255) / 256);

    static const long long expect[8] =
        {8388608, 1048576, 131072, 65536, 65536, 1048576, 64, 32};
    if (n_in != 8) {
        sentinel_kernel<<<outgrid, 256, 0, stream>>>(out, 20000.0f + 100.0f * n_in, NOUT);
        return;
    }
    for (int i = 0; i < 8; ++i) {
        if ((long long)in_sizes[i] != expect[i]) {
            sentinel_kernel<<<outgrid, 256, 0, stream>>>(out, 10000.0f + 1000.0f * i, NOUT);
            return;
        }
    }
    if (ws_size < 62914624ULL) {
        sentinel_kernel<<<outgrid, 256, 0, stream>>>(
            out, 30000.0f + (float)(ws_size >> 20), NOUT);
        return;
    }
    if (out_size != 8388608) {
        sentinel_kernel<<<outgrid, 256, 0, stream>>>(
            out, 512.0f * (1.0f + (float)(out_size >> 20)), NOUT);
        return;
    }

    const float* x   = (const float*)d_in[0];
    const float* Wq  = (const float*)d_in[1];
    const float* Wkv = (const float*)d_in[2];
    const float* Wk  = (const float*)d_in[3];
    const float* Wv  = (const float*)d_in[4];
    const float* Wo  = (const float*)d_in[5];
    const float* qg  = (const float*)d_in[6];
    const float* kg  = (const float*)d_in[7];

    char* base = (char*)d_ws + 64;
    bf16*  xb    = (bf16*)(base + 0);
    bf16*  wqT   = (bf16*)(base + 16777216);
    bf16*  wkvT  = (bf16*)(base + 18874368);
    bf16*  kvb   = (bf16*)(base + 19136512);
    bf16*  att_b = (bf16*)(base + 0);
    bf16*  vTb   = (bf16*)(base + 8388608);
    bf16*  qn    = (bf16*)(base + 35913728);
    bf16*  kn    = (bf16*)(base + 44302336);
    bf16*  vb    = (bf16*)(base + 52690944);
    bf16*  wkwvT = (bf16*)(base + 61079552);
    bf16*  woT   = (bf16*)(base + 61341696);

    const int BT = BB * TT;                    // 8192

    // 0. converts
    conv_x_kernel<<<outgrid, 256, 0, stream>>>(x, xb, NOUT);
    conv_trans_kernel<<<dim3(16, 16), 256, 0, stream>>>(Wq, wqT, 1024, 1024);
    conv_trans_kernel<<<dim3(2, 16), 256, 0, stream>>>(Wkv, wkvT, 1024, 128);
    conv_wkwv_kernel<<<512, 256, 0, stream>>>(Wk, Wv, wkwvT);
    conv_woT_kernel<<<dim3(16, 8), 256, 0, stream>>>(Wo, woT);

    // 1. qn = rmsnorm(xb @ Wq)[:, :32] * 0.125 (fused GEMM+RMS epilogue)
    gemm_qrms<<<dim3(8, 64), 256, 0, stream>>>(
        (const short*)xb, (const short*)wqT, qn, qg, BT, DD, DD);
    // 2. kvb = xb @ Wkv (64-row tiles -> 128 blocks), 8192x128, K=1024
    gemm_k64<<<dim3(1, 128), 256, 0, stream>>>(
        (const short*)xb, (const short*)wkvT, kvb, BT, LAT_, DD);
    // 3. kn/vb = fused(kvb @ [Wk|Wv]) (GEMM + K-RMS/V-split epilogue)
    gemm_kv<<<dim3(8, 64), 256, 0, stream>>>(
        (const short*)kvb, (const short*)wkwvT, kn, vb, kg, BT, 2 * 512, LAT_);
    // 4. vT = transpose(vb)
    vtrans_kernel<<<dim3(32, 64), 256, 0, stream>>>(vb, vTb);
    // 5. flash MFMA attention (no-max softmax, paired tiles, XCD swizzle)
    attn_mfma<<<dim3(16, 64), 256, 0, stream>>>(qn, kn, vTb, att_b);
    // 6. out = att_b @ Wo_remap (MFMA), 8192x1024, K=512
    gemm_mfma<float><<<dim3(8, 64), 256, 0, stream>>>(
        (const short*)att_b, (const short*)woT, out, BT, DD, 512);
}